// Round 1
// baseline (1227.305 us; speedup 1.0000x reference)
//
#include <hip/hip_runtime.h>
#include <cstdint>
#include <cstddef>

typedef unsigned short u16;
typedef unsigned int   u32;
typedef __bf16 bf16x8 __attribute__((ext_vector_type(8)));
typedef float  f32x4  __attribute__((ext_vector_type(4)));
static_assert(sizeof(bf16x8) == 16, "bf16x8 must be 16B");
static_assert(sizeof(f32x4) == 16, "f32x4 must be 16B");

#define DEVI static __device__ __forceinline__

// fp32 -> bf16, round-to-nearest-even
DEVI u16 f2bf(float x) {
  u32 u = __builtin_bit_cast(u32, x);
  u = (u + 0x7FFFu + ((u >> 16) & 1u)) >> 16;
  return (u16)u;
}

// ---------------------------------------------------------------------------
// Transpose + convert: W[K][N] fp32  ->  WT[N][K] bf16
// ---------------------------------------------------------------------------
__global__ __launch_bounds__(256) void transpose_cvt(const float* __restrict__ W,
                                                     u16* __restrict__ WT,
                                                     int K, int N) {
  __shared__ float tile[32][33];
  int tx = threadIdx.x & 31, ty = threadIdx.x >> 5;  // 32 x 8
  int c0 = blockIdx.x * 32, r0 = blockIdx.y * 32;
#pragma unroll
  for (int i = 0; i < 4; i++)
    tile[ty + i * 8][tx] = W[(size_t)(r0 + ty + i * 8) * N + c0 + tx];
  __syncthreads();
#pragma unroll
  for (int i = 0; i < 4; i++) {
    int r = ty + i * 8;
    WT[(size_t)(c0 + r) * K + r0 + tx] = f2bf(tile[tx][r]);
  }
}

// ---------------------------------------------------------------------------
// LayerNorm: X[row][1024] fp32 -> H[row][1024] bf16   (gamma, beta fp32)
// ---------------------------------------------------------------------------
__global__ __launch_bounds__(256) void ln_k(const float* __restrict__ X,
                                            const float* __restrict__ gam,
                                            const float* __restrict__ bet,
                                            u16* __restrict__ H) {
  __shared__ float2 part[4];
  int row = blockIdx.x, t = threadIdx.x;
  const float4* xr = (const float4*)(X + (size_t)row * 1024);
  float4 v = xr[t];
  float s = v.x + v.y + v.z + v.w;
  float q = v.x * v.x + v.y * v.y + v.z * v.z + v.w * v.w;
#pragma unroll
  for (int o = 32; o > 0; o >>= 1) {
    s += __shfl_xor(s, o);
    q += __shfl_xor(q, o);
  }
  if ((t & 63) == 0) part[t >> 6] = make_float2(s, q);
  __syncthreads();
  float S = part[0].x + part[1].x + part[2].x + part[3].x;
  float Q = part[0].y + part[1].y + part[2].y + part[3].y;
  float mu = S * (1.f / 1024.f);
  float rs = rsqrtf(Q * (1.f / 1024.f) - mu * mu + 1e-5f);
  float4 gv = ((const float4*)gam)[t];
  float4 bv = ((const float4*)bet)[t];
  ushort4 o;
  o.x = f2bf((v.x - mu) * rs * gv.x + bv.x);
  o.y = f2bf((v.y - mu) * rs * gv.y + bv.y);
  o.z = f2bf((v.z - mu) * rs * gv.z + bv.z);
  o.w = f2bf((v.w - mu) * rs * gv.w + bv.w);
  *(ushort4*)(H + (size_t)row * 1024 + t * 4) = o;
}

// ---------------------------------------------------------------------------
// GEMM: C[M][N] = A[M][K](bf16) @ Bt[N][K](bf16)^T + bias
// EPI 0: out bf16            EPI 1: out fp32, += res[idx]        EPI 2: gelu -> bf16
// 128x128 tile, BK=32, 4 waves (2x2), fragment-major LDS (conflict-free b128).
// ---------------------------------------------------------------------------
template <int EPI>
__global__ __launch_bounds__(256) void gemm_bt(const u16* __restrict__ A,
                                               const u16* __restrict__ Bt,
                                               const float* __restrict__ bias,
                                               const float* __restrict__ res,
                                               float* __restrict__ outF,
                                               u16* __restrict__ outB,
                                               int M, int N, int K) {
  __shared__ uint4 As[512];  // 8 frags x 64 lanes x 16B  (128 rows x 32 k)
  __shared__ uint4 Bs[512];
  const int t = threadIdx.x, lane = t & 63, wv = t >> 6;
  const int wr = wv >> 1, wc = wv & 1;
  const int bm0 = blockIdx.y * 128, bn0 = blockIdx.x * 128;

  f32x4 acc[4][4];
  const f32x4 z4 = {0.f, 0.f, 0.f, 0.f};
#pragma unroll
  for (int m = 0; m < 4; m++)
#pragma unroll
    for (int n = 0; n < 4; n++) acc[m][n] = z4;

  uint4 ar[2], br[2];
  auto loadAB = [&](int kt) {
#pragma unroll
    for (int bq = 0; bq < 2; bq++) {
      int c = t + bq * 256;                    // chunk id 0..511
      int row = ((c >> 6) << 4) + (c & 15);    // frag*16 + row-in-frag
      int ko = ((c >> 4) & 3) * 8;             // k-chunk * 8 elems
      ar[bq] = *(const uint4*)(A + (size_t)(bm0 + row) * K + kt * 32 + ko);
      br[bq] = *(const uint4*)(Bt + (size_t)(bn0 + row) * K + kt * 32 + ko);
    }
  };
  loadAB(0);
  const int KT = K >> 5;
  for (int kt = 0; kt < KT; kt++) {
    __syncthreads();
#pragma unroll
    for (int bq = 0; bq < 2; bq++) {
      int c = t + bq * 256;
      As[c] = ar[bq];
      Bs[c] = br[bq];
    }
    __syncthreads();
    if (kt + 1 < KT) loadAB(kt + 1);
    bf16x8 af[4], bf[4];
#pragma unroll
    for (int m = 0; m < 4; m++)
      af[m] = __builtin_bit_cast(bf16x8, As[(wr * 4 + m) * 64 + lane]);
#pragma unroll
    for (int n = 0; n < 4; n++)
      bf[n] = __builtin_bit_cast(bf16x8, Bs[(wc * 4 + n) * 64 + lane]);
#pragma unroll
    for (int m = 0; m < 4; m++)
#pragma unroll
      for (int n = 0; n < 4; n++)
        acc[m][n] = __builtin_amdgcn_mfma_f32_16x16x32_bf16(af[m], bf[n], acc[m][n], 0, 0, 0);
  }

  const int gh = lane >> 4, li = lane & 15;
#pragma unroll
  for (int n = 0; n < 4; n++) {
    int c = bn0 + wc * 64 + n * 16 + li;
    float bv = bias[c];
#pragma unroll
    for (int m = 0; m < 4; m++) {
      int rowb = bm0 + wr * 64 + m * 16 + gh * 4;
#pragma unroll
      for (int r = 0; r < 4; r++) {
        size_t idx = (size_t)(rowb + r) * N + c;
        float v = acc[m][n][r] + bv;
        if constexpr (EPI == 1) {
          v += res[idx];
          outF[idx] = v;
        } else if constexpr (EPI == 2) {
          v = 0.5f * v * (1.f + erff(v * 0.70710678118654752f));
          outB[idx] = f2bf(v);
        } else {
          outB[idx] = f2bf(v);
        }
      }
    }
  }
}

// ---------------------------------------------------------------------------
// Flash attention (bf16 MFMA, fp32 online softmax).
// qkv[row][3072] bf16: q cols 0..1023, k 1024..2047, v 2048..3071 (h*64+d).
// Block: 4 waves x 16 q-rows = 64 q rows. KV tile = 64 keys.
// S^T = mfma(K_frag, Q_frag)  -> lane holds col q = lane&15, keys 4*(lane>>4)+r.
// V stored transposed+key-permuted so P (packed 2x tiles) is a valid K=32 A-frag.
// ---------------------------------------------------------------------------
__global__ __launch_bounds__(256) void attn_k(const u16* __restrict__ qkv,
                                              u16* __restrict__ ao) {
  __shared__ uint4 Ks[512];    // 8 frags x 64 x 16B (fragment-major K tile)
  __shared__ u16 Vt[64 * 72];  // V^T, rows d (64), stride 72, key-permuted cols
  const int t = threadIdx.x, lane = t & 63, wv = t >> 6;
  const int g = lane >> 4, li = lane & 15;
  const int bb = blockIdx.y >> 4, h = blockIdx.y & 15;
  const int q0 = blockIdx.x * 64 + wv * 16;

  const size_t qoff = (size_t)(bb * 2048 + q0 + li) * 3072 + h * 64 + g * 8;
  bf16x8 qf0 = __builtin_bit_cast(bf16x8, *(const uint4*)(qkv + qoff));
  bf16x8 qf1 = __builtin_bit_cast(bf16x8, *(const uint4*)(qkv + qoff + 32));

  const f32x4 z4 = {0.f, 0.f, 0.f, 0.f};
  f32x4 Of[4];
#pragma unroll
  for (int db = 0; db < 4; db++) Of[db] = z4;
  float m_run = -INFINITY, l_run = 0.f;

  uint4 kr[2], vr[2];
  auto loadKV = [&](int k0) {
#pragma unroll
    for (int bq = 0; bq < 2; bq++) {
      int c = t + bq * 256;
      {
        int f = c >> 6, l2 = c & 63;
        int key = k0 + ((f >> 1) << 4) + (l2 & 15);
        int dd = (f & 1) * 32 + ((l2 >> 4) << 3);
        kr[bq] = *(const uint4*)(qkv + (size_t)(bb * 2048 + key) * 3072 + 1024 + h * 64 + dd);
      }
      {
        int p = c >> 3, d0 = (c & 7) * 8;
        vr[bq] = *(const uint4*)(qkv + (size_t)(bb * 2048 + k0 + p) * 3072 + 2048 + h * 64 + d0);
      }
    }
  };
  loadKV(0);

  for (int tile = 0; tile < 32; tile++) {
    __syncthreads();
#pragma unroll
    for (int bq = 0; bq < 2; bq++) {
      int c = t + bq * 256;
      Ks[c] = kr[bq];
      int p = c >> 3, d0 = (c & 7) * 8;
      // key permutation: phys p -> frag position (g32*32 + g*8 + t*4 + r)
      int kp = ((p >> 5) << 5) | (((p >> 2) & 3) << 3) | (((p >> 4) & 1) << 2) | (p & 3);
      u32 w0 = vr[bq].x, w1 = vr[bq].y, w2 = vr[bq].z, w3 = vr[bq].w;
      Vt[(d0 + 0) * 72 + kp] = (u16)w0;
      Vt[(d0 + 1) * 72 + kp] = (u16)(w0 >> 16);
      Vt[(d0 + 2) * 72 + kp] = (u16)w1;
      Vt[(d0 + 3) * 72 + kp] = (u16)(w1 >> 16);
      Vt[(d0 + 4) * 72 + kp] = (u16)w2;
      Vt[(d0 + 5) * 72 + kp] = (u16)(w2 >> 16);
      Vt[(d0 + 6) * 72 + kp] = (u16)w3;
      Vt[(d0 + 7) * 72 + kp] = (u16)(w3 >> 16);
    }
    __syncthreads();
    if (tile + 1 < 32) loadKV((tile + 1) * 64);

    // scores: S^T tiles (16 keys x 16 q), lane: q = li, keys = 4*g + r
    float sc[16];
    float mt = -INFINITY;
#pragma unroll
    for (int g32 = 0; g32 < 2; g32++) {
#pragma unroll
      for (int tt = 0; tt < 2; tt++) {
        int kb16 = g32 * 2 + tt;
        bf16x8 k0f = __builtin_bit_cast(bf16x8, Ks[(kb16 * 2 + 0) * 64 + lane]);
        bf16x8 k1f = __builtin_bit_cast(bf16x8, Ks[(kb16 * 2 + 1) * 64 + lane]);
        f32x4 st = z4;
        st = __builtin_amdgcn_mfma_f32_16x16x32_bf16(k0f, qf0, st, 0, 0, 0);
        st = __builtin_amdgcn_mfma_f32_16x16x32_bf16(k1f, qf1, st, 0, 0, 0);
#pragma unroll
        for (int r = 0; r < 4; r++) {
          float s = st[r] * 0.125f;
          sc[g32 * 8 + tt * 4 + r] = s;
          mt = fmaxf(mt, s);
        }
      }
    }
    mt = fmaxf(mt, __shfl_xor(mt, 16));
    mt = fmaxf(mt, __shfl_xor(mt, 32));
    float mn = fmaxf(m_run, mt);
    float aa = __expf(m_run - mn);
    float ps = 0.f;
#pragma unroll
    for (int i = 0; i < 16; i++) {
      float p = __expf(sc[i] - mn);
      sc[i] = p;
      ps += p;
    }
    ps += __shfl_xor(ps, 16);
    ps += __shfl_xor(ps, 32);
    l_run = l_run * aa + ps;
    m_run = mn;
    // rescale O: O rows are q = 4*g + r; a for that q held at lane (4*g+r)
    float a0 = __shfl(aa, g * 4 + 0);
    float a1 = __shfl(aa, g * 4 + 1);
    float a2 = __shfl(aa, g * 4 + 2);
    float a3 = __shfl(aa, g * 4 + 3);
#pragma unroll
    for (int db = 0; db < 4; db++) {
      Of[db][0] *= a0;
      Of[db][1] *= a1;
      Of[db][2] *= a2;
      Of[db][3] *= a3;
    }
    // PV: P(g32) is a K=32 A-frag (q rows = li, k = permuted keys 8*g + j)
#pragma unroll
    for (int g32 = 0; g32 < 2; g32++) {
      bf16x8 pf;
#pragma unroll
      for (int j = 0; j < 8; j++) pf[j] = (__bf16)sc[g32 * 8 + j];
#pragma unroll
      for (int db = 0; db < 4; db++) {
        bf16x8 vf = __builtin_bit_cast(
            bf16x8, *(const uint4*)&Vt[(db * 16 + li) * 72 + g32 * 32 + g * 8]);
        Of[db] = __builtin_amdgcn_mfma_f32_16x16x32_bf16(pf, vf, Of[db], 0, 0, 0);
      }
    }
  }

  float invl[4];
#pragma unroll
  for (int r = 0; r < 4; r++) invl[r] = 1.f / __shfl(l_run, g * 4 + r);
#pragma unroll
  for (int db = 0; db < 4; db++)
#pragma unroll
    for (int r = 0; r < 4; r++)
      ao[(size_t)(bb * 2048 + q0 + 4 * g + r) * 1024 + h * 64 + db * 16 + li] =
          f2bf(Of[db][r] * invl[r]);
}

// ---------------------------------------------------------------------------
// Launcher
// ---------------------------------------------------------------------------
extern "C" void kernel_launch(void* const* d_in, const int* in_sizes, int n_in,
                              void* d_out, int out_size, void* d_ws, size_t ws_size,
                              hipStream_t stream) {
  const float* x = (const float*)d_in[0];
  const float* ln1g = (const float*)d_in[1];
  const float* ln1b = (const float*)d_in[2];
  const float* wqkv = (const float*)d_in[3];
  const float* bqkv = (const float*)d_in[4];
  const float* wout = (const float*)d_in[5];
  const float* bout = (const float*)d_in[6];
  const float* ln2g = (const float*)d_in[7];
  const float* ln2b = (const float*)d_in[8];
  const float* wff1 = (const float*)d_in[9];
  const float* bff1 = (const float*)d_in[10];
  const float* wff2 = (const float*)d_in[11];
  const float* bff2 = (const float*)d_in[12];
  float* outF = (float*)d_out;
  char* ws = (char*)d_ws;

  u16* wqkvT = (u16*)(ws + 0);         // 3072x1024 bf16 : 6291456 B
  u16* woutT = (u16*)(ws + 6291456);   // 1024x1024 bf16 : 2097152 B
  u16* wff1T = (u16*)(ws + 8388608);   // 4096x1024 bf16 : 8388608 B
  u16* wff2T = (u16*)(ws + 16777216);  // 1024x4096 bf16 : 8388608 B
  u16* hbuf  = (u16*)(ws + 25165824);  // 8192x1024 bf16 : 16777216 B
  u16* qkvb  = (u16*)(ws + 41943040);  // 8192x3072 bf16 : 50331648 B
  u16* attnb = (u16*)(ws + 92274688);  // 8192x1024 bf16 : 16777216 B
  u16* ffn1b = qkvb;                   // 8192x4096 bf16 overlays qkv+attn (dead by then)

  transpose_cvt<<<dim3(96, 32), 256, 0, stream>>>(wqkv, wqkvT, 1024, 3072);
  transpose_cvt<<<dim3(32, 32), 256, 0, stream>>>(wout, woutT, 1024, 1024);
  transpose_cvt<<<dim3(128, 32), 256, 0, stream>>>(wff1, wff1T, 1024, 4096);
  transpose_cvt<<<dim3(32, 128), 256, 0, stream>>>(wff2, wff2T, 4096, 1024);

  ln_k<<<8192, 256, 0, stream>>>(x, ln1g, ln1b, hbuf);
  gemm_bt<0><<<dim3(24, 64), 256, 0, stream>>>(hbuf, wqkvT, bqkv, nullptr, nullptr, qkvb,
                                               8192, 3072, 1024);
  attn_k<<<dim3(32, 64), 256, 0, stream>>>(qkvb, attnb);
  gemm_bt<1><<<dim3(8, 64), 256, 0, stream>>>(attnb, woutT, bout, x, outF, nullptr,
                                              8192, 1024, 1024);
  ln_k<<<8192, 256, 0, stream>>>(outF, ln2g, ln2b, hbuf);
  gemm_bt<2><<<dim3(32, 64), 256, 0, stream>>>(hbuf, wff1T, bff1, nullptr, nullptr, ffn1b,
                                               8192, 4096, 1024);
  gemm_bt<1><<<dim3(8, 64), 256, 0, stream>>>(ffn1b, wff2T, bff2, outF, outF, nullptr,
                                              8192, 1024, 4096);

  (void)in_sizes;
  (void)n_in;
  (void)out_size;
  (void)ws_size;
}

// Round 2
// 685.776 us; speedup vs baseline: 1.7897x; 1.7897x over previous
//
#include <hip/hip_runtime.h>
#include <cstdint>
#include <cstddef>

typedef unsigned short u16;
typedef unsigned int   u32;
typedef __bf16 bf16x8 __attribute__((ext_vector_type(8)));
typedef float  f32x4  __attribute__((ext_vector_type(4)));
static_assert(sizeof(bf16x8) == 16, "bf16x8 must be 16B");
static_assert(sizeof(f32x4) == 16, "f32x4 must be 16B");

#define DEVI static __device__ __forceinline__

// fp32 -> bf16, round-to-nearest-even
DEVI u16 f2bf(float x) {
  u32 u = __builtin_bit_cast(u32, x);
  u = (u + 0x7FFFu + ((u >> 16) & 1u)) >> 16;
  return (u16)u;
}

// direct HBM -> LDS, 16 bytes per lane. LDS dest must be wave-uniform base;
// HW writes base + lane*16. Global source is per-lane.
DEVI void gload16(const u16* g, u16* l) {
  __builtin_amdgcn_global_load_lds(
      (const __attribute__((address_space(1))) void*)g,
      (__attribute__((address_space(3))) void*)l, 16, 0, 0);
}

// ---------------------------------------------------------------------------
// Transpose + convert: W[K][N] fp32  ->  WT[N][K] bf16
// ---------------------------------------------------------------------------
__global__ __launch_bounds__(256) void transpose_cvt(const float* __restrict__ W,
                                                     u16* __restrict__ WT,
                                                     int K, int N) {
  __shared__ float tile[32][33];
  int tx = threadIdx.x & 31, ty = threadIdx.x >> 5;  // 32 x 8
  int c0 = blockIdx.x * 32, r0 = blockIdx.y * 32;
#pragma unroll
  for (int i = 0; i < 4; i++)
    tile[ty + i * 8][tx] = W[(size_t)(r0 + ty + i * 8) * N + c0 + tx];
  __syncthreads();
#pragma unroll
  for (int i = 0; i < 4; i++) {
    int r = ty + i * 8;
    WT[(size_t)(c0 + r) * K + r0 + tx] = f2bf(tile[tx][r]);
  }
}

// ---------------------------------------------------------------------------
// LayerNorm: X[row][1024] fp32 -> H[row][1024] bf16   (gamma, beta fp32)
// ---------------------------------------------------------------------------
__global__ __launch_bounds__(256) void ln_k(const float* __restrict__ X,
                                            const float* __restrict__ gam,
                                            const float* __restrict__ bet,
                                            u16* __restrict__ H) {
  __shared__ float2 part[4];
  int row = blockIdx.x, t = threadIdx.x;
  const float4* xr = (const float4*)(X + (size_t)row * 1024);
  float4 v = xr[t];
  float s = v.x + v.y + v.z + v.w;
  float q = v.x * v.x + v.y * v.y + v.z * v.z + v.w * v.w;
#pragma unroll
  for (int o = 32; o > 0; o >>= 1) {
    s += __shfl_xor(s, o);
    q += __shfl_xor(q, o);
  }
  if ((t & 63) == 0) part[t >> 6] = make_float2(s, q);
  __syncthreads();
  float S = part[0].x + part[1].x + part[2].x + part[3].x;
  float Q = part[0].y + part[1].y + part[2].y + part[3].y;
  float mu = S * (1.f / 1024.f);
  float rs = rsqrtf(Q * (1.f / 1024.f) - mu * mu + 1e-5f);
  float4 gv = ((const float4*)gam)[t];
  float4 bv = ((const float4*)bet)[t];
  ushort4 o;
  o.x = f2bf((v.x - mu) * rs * gv.x + bv.x);
  o.y = f2bf((v.y - mu) * rs * gv.y + bv.y);
  o.z = f2bf((v.z - mu) * rs * gv.z + bv.z);
  o.w = f2bf((v.w - mu) * rs * gv.w + bv.w);
  *(ushort4*)(H + (size_t)row * 1024 + t * 4) = o;
}

// ---------------------------------------------------------------------------
// GEMM: C[M][N] = A[M][K](bf16) @ Bt[N][K](bf16)^T + bias
// EPI 0: out bf16            EPI 1: out fp32, += res[idx]        EPI 2: gelu -> bf16
// 128x128 tile, BK=32, 4 waves (2x2), fragment-major LDS (conflict-free b128),
// global_load_lds width-16 staging (m97 structure), XCD-aware block swizzle.
// ---------------------------------------------------------------------------
template <int EPI>
__global__ __launch_bounds__(256, 4) void gemm_bt(const u16* __restrict__ A,
                                                  const u16* __restrict__ Bt,
                                                  const float* __restrict__ bias,
                                                  const float* __restrict__ res,
                                                  float* __restrict__ outF,
                                                  u16* __restrict__ outB,
                                                  int M, int N, int K) {
  __shared__ uint4 As[512];  // 8 frags x 64 lanes x 16B  (128 rows x 32 k)
  __shared__ uint4 Bs[512];
  const int t = threadIdx.x, lane = t & 63, wv = t >> 6;
  const int wr = wv >> 1, wc = wv & 1;

  // XCD-aware bijective swizzle (all grids here have nwg % 8 == 0)
  const int nwg = gridDim.x * gridDim.y;
  const int wg = blockIdx.y * gridDim.x + blockIdx.x;
  const int swz = (wg & 7) * (nwg >> 3) + (wg >> 3);
  const int bx = swz % gridDim.x, by = swz / gridDim.x;
  const int bm0 = by * 128, bn0 = bx * 128;

  f32x4 acc[4][4];
  const f32x4 z4 = {0.f, 0.f, 0.f, 0.f};
#pragma unroll
  for (int m = 0; m < 4; m++)
#pragma unroll
    for (int n = 0; n < 4; n++) acc[m][n] = z4;

  // staging source addresses: chunk c = bq*256 + t; row = (c>>6)*16 + (c&15),
  // k-chunk = ((c>>4)&3)*8.  bq=1 is just +64 rows (bits 4..5 unchanged).
  const int row0 = ((t >> 6) << 4) + (t & 15);
  const int ko0 = ((t >> 4) & 3) * 8;
  const u16* a0 = A + (size_t)(bm0 + row0) * K + ko0;
  const u16* b0 = Bt + (size_t)(bn0 + row0) * K + ko0;
  const size_t rstep = (size_t)64 * K;

  const int KT = K >> 5;
  for (int kt = 0; kt < KT; kt++) {
    __syncthreads();  // previous tile's reads done before overwrite
    {
      const u16* ga = a0 + kt * 32;
      const u16* gb = b0 + kt * 32;
      gload16(ga, (u16*)&As[wv * 64]);
      gload16(gb, (u16*)&Bs[wv * 64]);
      gload16(ga + rstep, (u16*)&As[256 + wv * 64]);
      gload16(gb + rstep, (u16*)&Bs[256 + wv * 64]);
    }
    __syncthreads();  // compiler drains vmcnt(0) here: tile ready
    bf16x8 af[4], bf[4];
#pragma unroll
    for (int m = 0; m < 4; m++)
      af[m] = __builtin_bit_cast(bf16x8, As[(wr * 4 + m) * 64 + lane]);
#pragma unroll
    for (int n = 0; n < 4; n++)
      bf[n] = __builtin_bit_cast(bf16x8, Bs[(wc * 4 + n) * 64 + lane]);
#pragma unroll
    for (int m = 0; m < 4; m++)
#pragma unroll
      for (int n = 0; n < 4; n++)
        acc[m][n] = __builtin_amdgcn_mfma_f32_16x16x32_bf16(af[m], bf[n], acc[m][n], 0, 0, 0);
  }

  const int gh = lane >> 4, li = lane & 15;
#pragma unroll
  for (int n = 0; n < 4; n++) {
    int c = bn0 + wc * 64 + n * 16 + li;
    float bv = bias[c];
#pragma unroll
    for (int m = 0; m < 4; m++) {
      int rowb = bm0 + wr * 64 + m * 16 + gh * 4;
#pragma unroll
      for (int r = 0; r < 4; r++) {
        size_t idx = (size_t)(rowb + r) * N + c;
        float v = acc[m][n][r] + bv;
        if constexpr (EPI == 1) {
          v += res[idx];
          outF[idx] = v;
        } else if constexpr (EPI == 2) {
          v = 0.5f * v * (1.f + erff(v * 0.70710678118654752f));
          outB[idx] = f2bf(v);
        } else {
          outB[idx] = f2bf(v);
        }
      }
    }
  }
}

// ---------------------------------------------------------------------------
// Flash attention (bf16 MFMA, fp32 online softmax).
// qkv[row][3072] bf16: q cols 0..1023, k 1024..2047, v 2048..3071 (h*64+d).
// Block: 4 waves x 16 q-rows = 64 q rows. KV tile = 64 keys.
// S^T = mfma(K_frag, Q_frag)  -> lane holds col q = lane&15, keys 4*(lane>>4)+r.
// V stored transposed+key-permuted so P (packed 2x tiles) is a valid K=32 A-frag.
// ---------------------------------------------------------------------------
__global__ __launch_bounds__(256) void attn_k(const u16* __restrict__ qkv,
                                              u16* __restrict__ ao) {
  __shared__ uint4 Ks[512];    // 8 frags x 64 x 16B (fragment-major K tile)
  __shared__ u16 Vt[64 * 72];  // V^T, rows d (64), stride 72, key-permuted cols
  const int t = threadIdx.x, lane = t & 63, wv = t >> 6;
  const int g = lane >> 4, li = lane & 15;
  const int bb = blockIdx.y >> 4, h = blockIdx.y & 15;
  const int q0 = blockIdx.x * 64 + wv * 16;

  const size_t qoff = (size_t)(bb * 2048 + q0 + li) * 3072 + h * 64 + g * 8;
  bf16x8 qf0 = __builtin_bit_cast(bf16x8, *(const uint4*)(qkv + qoff));
  bf16x8 qf1 = __builtin_bit_cast(bf16x8, *(const uint4*)(qkv + qoff + 32));

  const f32x4 z4 = {0.f, 0.f, 0.f, 0.f};
  f32x4 Of[4];
#pragma unroll
  for (int db = 0; db < 4; db++) Of[db] = z4;
  float m_run = -INFINITY, l_run = 0.f;

  uint4 kr[2], vr[2];
  auto loadKV = [&](int k0) {
#pragma unroll
    for (int bq = 0; bq < 2; bq++) {
      int c = t + bq * 256;
      {
        int f = c >> 6, l2 = c & 63;
        int key = k0 + ((f >> 1) << 4) + (l2 & 15);
        int dd = (f & 1) * 32 + ((l2 >> 4) << 3);
        kr[bq] = *(const uint4*)(qkv + (size_t)(bb * 2048 + key) * 3072 + 1024 + h * 64 + dd);
      }
      {
        int p = c >> 3, d0 = (c & 7) * 8;
        vr[bq] = *(const uint4*)(qkv + (size_t)(bb * 2048 + k0 + p) * 3072 + 2048 + h * 64 + d0);
      }
    }
  };
  loadKV(0);

  for (int tile = 0; tile < 32; tile++) {
    __syncthreads();
#pragma unroll
    for (int bq = 0; bq < 2; bq++) {
      int c = t + bq * 256;
      Ks[c] = kr[bq];
      int p = c >> 3, d0 = (c & 7) * 8;
      // key permutation: phys p -> frag position (g32*32 + g*8 + t*4 + r)
      int kp = ((p >> 5) << 5) | (((p >> 2) & 3) << 3) | (((p >> 4) & 1) << 2) | (p & 3);
      u32 w0 = vr[bq].x, w1 = vr[bq].y, w2 = vr[bq].z, w3 = vr[bq].w;
      Vt[(d0 + 0) * 72 + kp] = (u16)w0;
      Vt[(d0 + 1) * 72 + kp] = (u16)(w0 >> 16);
      Vt[(d0 + 2) * 72 + kp] = (u16)w1;
      Vt[(d0 + 3) * 72 + kp] = (u16)(w1 >> 16);
      Vt[(d0 + 4) * 72 + kp] = (u16)w2;
      Vt[(d0 + 5) * 72 + kp] = (u16)(w2 >> 16);
      Vt[(d0 + 6) * 72 + kp] = (u16)w3;
      Vt[(d0 + 7) * 72 + kp] = (u16)(w3 >> 16);
    }
    __syncthreads();
    if (tile + 1 < 32) loadKV((tile + 1) * 64);

    // scores: S^T tiles (16 keys x 16 q), lane: q = li, keys = 4*g + r
    float sc[16];
    float mt = -INFINITY;
#pragma unroll
    for (int g32 = 0; g32 < 2; g32++) {
#pragma unroll
      for (int tt = 0; tt < 2; tt++) {
        int kb16 = g32 * 2 + tt;
        bf16x8 k0f = __builtin_bit_cast(bf16x8, Ks[(kb16 * 2 + 0) * 64 + lane]);
        bf16x8 k1f = __builtin_bit_cast(bf16x8, Ks[(kb16 * 2 + 1) * 64 + lane]);
        f32x4 st = z4;
        st = __builtin_amdgcn_mfma_f32_16x16x32_bf16(k0f, qf0, st, 0, 0, 0);
        st = __builtin_amdgcn_mfma_f32_16x16x32_bf16(k1f, qf1, st, 0, 0, 0);
#pragma unroll
        for (int r = 0; r < 4; r++) {
          float s = st[r] * 0.125f;
          sc[g32 * 8 + tt * 4 + r] = s;
          mt = fmaxf(mt, s);
        }
      }
    }
    mt = fmaxf(mt, __shfl_xor(mt, 16));
    mt = fmaxf(mt, __shfl_xor(mt, 32));
    float mn = fmaxf(m_run, mt);
    float aa = __expf(m_run - mn);
    float ps = 0.f;
#pragma unroll
    for (int i = 0; i < 16; i++) {
      float p = __expf(sc[i] - mn);
      sc[i] = p;
      ps += p;
    }
    ps += __shfl_xor(ps, 16);
    ps += __shfl_xor(ps, 32);
    l_run = l_run * aa + ps;
    m_run = mn;
    // rescale O: O rows are q = 4*g + r; a for that q held at lane (4*g+r)
    float a0 = __shfl(aa, g * 4 + 0);
    float a1 = __shfl(aa, g * 4 + 1);
    float a2 = __shfl(aa, g * 4 + 2);
    float a3 = __shfl(aa, g * 4 + 3);
#pragma unroll
    for (int db = 0; db < 4; db++) {
      Of[db][0] *= a0;
      Of[db][1] *= a1;
      Of[db][2] *= a2;
      Of[db][3] *= a3;
    }
    // PV: P(g32) is a K=32 A-frag (q rows = li, k = permuted keys 8*g + j)
#pragma unroll
    for (int g32 = 0; g32 < 2; g32++) {
      bf16x8 pf;
#pragma unroll
      for (int j = 0; j < 8; j++) pf[j] = (__bf16)sc[g32 * 8 + j];
#pragma unroll
      for (int db = 0; db < 4; db++) {
        bf16x8 vf = __builtin_bit_cast(
            bf16x8, *(const uint4*)&Vt[(db * 16 + li) * 72 + g32 * 32 + g * 8]);
        Of[db] = __builtin_amdgcn_mfma_f32_16x16x32_bf16(pf, vf, Of[db], 0, 0, 0);
      }
    }
  }

  float invl[4];
#pragma unroll
  for (int r = 0; r < 4; r++) invl[r] = 1.f / __shfl(l_run, g * 4 + r);
#pragma unroll
  for (int db = 0; db < 4; db++)
#pragma unroll
    for (int r = 0; r < 4; r++)
      ao[(size_t)(bb * 2048 + q0 + 4 * g + r) * 1024 + h * 64 + db * 16 + li] =
          f2bf(Of[db][r] * invl[r]);
}

// ---------------------------------------------------------------------------
// Launcher
// ---------------------------------------------------------------------------
extern "C" void kernel_launch(void* const* d_in, const int* in_sizes, int n_in,
                              void* d_out, int out_size, void* d_ws, size_t ws_size,
                              hipStream_t stream) {
  const float* x = (const float*)d_in[0];
  const float* ln1g = (const float*)d_in[1];
  const float* ln1b = (const float*)d_in[2];
  const float* wqkv = (const float*)d_in[3];
  const float* bqkv = (const float*)d_in[4];
  const float* wout = (const float*)d_in[5];
  const float* bout = (const float*)d_in[6];
  const float* ln2g = (const float*)d_in[7];
  const float* ln2b = (const float*)d_in[8];
  const float* wff1 = (const float*)d_in[9];
  const float* bff1 = (const float*)d_in[10];
  const float* wff2 = (const float*)d_in[11];
  const float* bff2 = (const float*)d_in[12];
  float* outF = (float*)d_out;
  char* ws = (char*)d_ws;

  u16* wqkvT = (u16*)(ws + 0);         // 3072x1024 bf16 : 6291456 B
  u16* woutT = (u16*)(ws + 6291456);   // 1024x1024 bf16 : 2097152 B
  u16* wff1T = (u16*)(ws + 8388608);   // 4096x1024 bf16 : 8388608 B
  u16* wff2T = (u16*)(ws + 16777216);  // 1024x4096 bf16 : 8388608 B
  u16* hbuf  = (u16*)(ws + 25165824);  // 8192x1024 bf16 : 16777216 B
  u16* qkvb  = (u16*)(ws + 41943040);  // 8192x3072 bf16 : 50331648 B
  u16* attnb = (u16*)(ws + 92274688);  // 8192x1024 bf16 : 16777216 B
  u16* ffn1b = qkvb;                   // 8192x4096 bf16 overlays qkv+attn (dead by then)

  transpose_cvt<<<dim3(96, 32), 256, 0, stream>>>(wqkv, wqkvT, 1024, 3072);
  transpose_cvt<<<dim3(32, 32), 256, 0, stream>>>(wout, woutT, 1024, 1024);
  transpose_cvt<<<dim3(128, 32), 256, 0, stream>>>(wff1, wff1T, 1024, 4096);
  transpose_cvt<<<dim3(32, 128), 256, 0, stream>>>(wff2, wff2T, 4096, 1024);

  ln_k<<<8192, 256, 0, stream>>>(x, ln1g, ln1b, hbuf);
  gemm_bt<0><<<dim3(24, 64), 256, 0, stream>>>(hbuf, wqkvT, bqkv, nullptr, nullptr, qkvb,
                                               8192, 3072, 1024);
  attn_k<<<dim3(32, 64), 256, 0, stream>>>(qkvb, attnb);
  gemm_bt<1><<<dim3(8, 64), 256, 0, stream>>>(attnb, woutT, bout, x, outF, nullptr,
                                              8192, 1024, 1024);
  ln_k<<<8192, 256, 0, stream>>>(outF, ln2g, ln2b, hbuf);
  gemm_bt<2><<<dim3(32, 64), 256, 0, stream>>>(hbuf, wff1T, bff1, nullptr, nullptr, ffn1b,
                                               8192, 4096, 1024);
  gemm_bt<1><<<dim3(8, 64), 256, 0, stream>>>(ffn1b, wff2T, bff2, outF, outF, nullptr,
                                              8192, 1024, 4096);

  (void)in_sizes;
  (void)n_in;
  (void)out_size;
  (void)ws_size;
}

// Round 3
// 588.385 us; speedup vs baseline: 2.0859x; 1.1655x over previous
//
#include <hip/hip_runtime.h>
#include <cstdint>
#include <cstddef>

typedef unsigned short u16;
typedef unsigned int   u32;
typedef __bf16 bf16x8 __attribute__((ext_vector_type(8)));
typedef float  f32x4  __attribute__((ext_vector_type(4)));
static_assert(sizeof(bf16x8) == 16, "bf16x8 must be 16B");
static_assert(sizeof(f32x4) == 16, "f32x4 must be 16B");

#define DEVI static __device__ __forceinline__

// fp32 -> bf16, round-to-nearest-even
DEVI u16 f2bf(float x) {
  u32 u = __builtin_bit_cast(u32, x);
  u = (u + 0x7FFFu + ((u >> 16) & 1u)) >> 16;
  return (u16)u;
}

// direct HBM -> LDS, 16 bytes per lane. LDS dest must be wave-uniform base;
// HW writes base + lane*16. Global source is per-lane.
DEVI void gload16(const u16* g, u16* l) {
  __builtin_amdgcn_global_load_lds(
      (const __attribute__((address_space(1))) void*)g,
      (__attribute__((address_space(3))) void*)l, 16, 0, 0);
}

// ---------------------------------------------------------------------------
// Transpose + convert: W[K][N] fp32  ->  WT[N][K] bf16
// ---------------------------------------------------------------------------
__global__ __launch_bounds__(256) void transpose_cvt(const float* __restrict__ W,
                                                     u16* __restrict__ WT,
                                                     int K, int N) {
  __shared__ float tile[32][33];
  int tx = threadIdx.x & 31, ty = threadIdx.x >> 5;  // 32 x 8
  int c0 = blockIdx.x * 32, r0 = blockIdx.y * 32;
#pragma unroll
  for (int i = 0; i < 4; i++)
    tile[ty + i * 8][tx] = W[(size_t)(r0 + ty + i * 8) * N + c0 + tx];
  __syncthreads();
#pragma unroll
  for (int i = 0; i < 4; i++) {
    int r = ty + i * 8;
    WT[(size_t)(c0 + r) * K + r0 + tx] = f2bf(tile[tx][r]);
  }
}

// ---------------------------------------------------------------------------
// LayerNorm: X[row][1024] fp32 -> H[row][1024] bf16   (gamma, beta fp32)
// ---------------------------------------------------------------------------
__global__ __launch_bounds__(256) void ln_k(const float* __restrict__ X,
                                            const float* __restrict__ gam,
                                            const float* __restrict__ bet,
                                            u16* __restrict__ H) {
  __shared__ float2 part[4];
  int row = blockIdx.x, t = threadIdx.x;
  const float4* xr = (const float4*)(X + (size_t)row * 1024);
  float4 v = xr[t];
  float s = v.x + v.y + v.z + v.w;
  float q = v.x * v.x + v.y * v.y + v.z * v.z + v.w * v.w;
#pragma unroll
  for (int o = 32; o > 0; o >>= 1) {
    s += __shfl_xor(s, o);
    q += __shfl_xor(q, o);
  }
  if ((t & 63) == 0) part[t >> 6] = make_float2(s, q);
  __syncthreads();
  float S = part[0].x + part[1].x + part[2].x + part[3].x;
  float Q = part[0].y + part[1].y + part[2].y + part[3].y;
  float mu = S * (1.f / 1024.f);
  float rs = rsqrtf(Q * (1.f / 1024.f) - mu * mu + 1e-5f);
  float4 gv = ((const float4*)gam)[t];
  float4 bv = ((const float4*)bet)[t];
  ushort4 o;
  o.x = f2bf((v.x - mu) * rs * gv.x + bv.x);
  o.y = f2bf((v.y - mu) * rs * gv.y + bv.y);
  o.z = f2bf((v.z - mu) * rs * gv.z + bv.z);
  o.w = f2bf((v.w - mu) * rs * gv.w + bv.w);
  *(ushort4*)(H + (size_t)row * 1024 + t * 4) = o;
}

// ---------------------------------------------------------------------------
// GEMM: C[M][N] = A[M][K](bf16) @ Bt[N][K](bf16)^T + bias
// EPI 0: out bf16            EPI 1: out fp32, += res[idx]        EPI 2: gelu -> bf16
// 128x128 tile, BK=32, 4 waves (2x2), fragment-major LDS (conflict-free b128),
// global_load_lds width-16 staging (m97 structure), XCD-aware block swizzle.
// ---------------------------------------------------------------------------
template <int EPI>
__global__ __launch_bounds__(256, 4) void gemm_bt(const u16* __restrict__ A,
                                                  const u16* __restrict__ Bt,
                                                  const float* __restrict__ bias,
                                                  const float* __restrict__ res,
                                                  float* __restrict__ outF,
                                                  u16* __restrict__ outB,
                                                  int M, int N, int K) {
  __shared__ uint4 As[512];  // 8 frags x 64 lanes x 16B  (128 rows x 32 k)
  __shared__ uint4 Bs[512];
  const int t = threadIdx.x, lane = t & 63, wv = t >> 6;
  const int wr = wv >> 1, wc = wv & 1;

  // XCD-aware bijective swizzle (all grids here have nwg % 8 == 0)
  const int nwg = gridDim.x * gridDim.y;
  const int wg = blockIdx.y * gridDim.x + blockIdx.x;
  const int swz = (wg & 7) * (nwg >> 3) + (wg >> 3);
  const int bx = swz % gridDim.x, by = swz / gridDim.x;
  const int bm0 = by * 128, bn0 = bx * 128;

  f32x4 acc[4][4];
  const f32x4 z4 = {0.f, 0.f, 0.f, 0.f};
#pragma unroll
  for (int m = 0; m < 4; m++)
#pragma unroll
    for (int n = 0; n < 4; n++) acc[m][n] = z4;

  // staging source addresses: chunk c = bq*256 + t; row = (c>>6)*16 + (c&15),
  // k-chunk = ((c>>4)&3)*8.  bq=1 is just +64 rows (bits 4..5 unchanged).
  const int row0 = ((t >> 6) << 4) + (t & 15);
  const int ko0 = ((t >> 4) & 3) * 8;
  const u16* a0 = A + (size_t)(bm0 + row0) * K + ko0;
  const u16* b0 = Bt + (size_t)(bn0 + row0) * K + ko0;
  const size_t rstep = (size_t)64 * K;

  const int KT = K >> 5;
  for (int kt = 0; kt < KT; kt++) {
    __syncthreads();  // previous tile's reads done before overwrite
    {
      const u16* ga = a0 + kt * 32;
      const u16* gb = b0 + kt * 32;
      gload16(ga, (u16*)&As[wv * 64]);
      gload16(gb, (u16*)&Bs[wv * 64]);
      gload16(ga + rstep, (u16*)&As[256 + wv * 64]);
      gload16(gb + rstep, (u16*)&Bs[256 + wv * 64]);
    }
    __syncthreads();  // compiler drains vmcnt(0) here: tile ready
    bf16x8 af[4], bf[4];
#pragma unroll
    for (int m = 0; m < 4; m++)
      af[m] = __builtin_bit_cast(bf16x8, As[(wr * 4 + m) * 64 + lane]);
#pragma unroll
    for (int n = 0; n < 4; n++)
      bf[n] = __builtin_bit_cast(bf16x8, Bs[(wc * 4 + n) * 64 + lane]);
#pragma unroll
    for (int m = 0; m < 4; m++)
#pragma unroll
      for (int n = 0; n < 4; n++)
        acc[m][n] = __builtin_amdgcn_mfma_f32_16x16x32_bf16(af[m], bf[n], acc[m][n], 0, 0, 0);
  }

  const int gh = lane >> 4, li = lane & 15;
#pragma unroll
  for (int n = 0; n < 4; n++) {
    int c = bn0 + wc * 64 + n * 16 + li;
    float bv = bias[c];
#pragma unroll
    for (int m = 0; m < 4; m++) {
      int rowb = bm0 + wr * 64 + m * 16 + gh * 4;
#pragma unroll
      for (int r = 0; r < 4; r++) {
        size_t idx = (size_t)(rowb + r) * N + c;
        float v = acc[m][n][r] + bv;
        if constexpr (EPI == 1) {
          v += res[idx];
          outF[idx] = v;
        } else if constexpr (EPI == 2) {
          v = 0.5f * v * (1.f + erff(v * 0.70710678118654752f));
          outB[idx] = f2bf(v);
        } else {
          outB[idx] = f2bf(v);
        }
      }
    }
  }
}

// ---------------------------------------------------------------------------
// V transpose: qkv V-section -> fragment-major V^T buffer
// vfm layout: [bh][kt(32)][frag(8)][lane(64)][8 u16], frag = db*2 + g32.
// Fragment slot e of lane (g=lane>>4, li=lane&15) holds
//   V[phys key = g32*32 + (e>>2)*16 + g*4 + (e&3)][db*16 + li]
// -- the exact permutation the attention P-fragments produce.
// ---------------------------------------------------------------------------
__global__ __launch_bounds__(256) void v_tr(const u16* __restrict__ qkv,
                                            u16* __restrict__ vfm) {
  __shared__ u16 Vl[64 * 72];
  const int t = threadIdx.x;
  const int bh = blockIdx.y;  // bb*16 + h
  const int bb = bh >> 4, h = bh & 15;
  const int kt = blockIdx.x;  // 0..31
#pragma unroll
  for (int bq = 0; bq < 2; bq++) {
    int c = t + bq * 256;  // 0..511
    int key = c >> 3, d0 = (c & 7) * 8;
    uint4 v = *(const uint4*)(qkv + (size_t)(bb * 2048 + kt * 64 + key) * 3072 + 2048 +
                              h * 64 + d0);
    *(uint4*)&Vl[key * 72 + d0] = v;
  }
  __syncthreads();
#pragma unroll
  for (int bq = 0; bq < 2; bq++) {
    int oc = t + bq * 256;
    int f = oc >> 6, l = oc & 63;
    int db = f >> 1, g32 = f & 1;
    int li = l & 15, g = l >> 4;
    u16 tmp[8];
#pragma unroll
    for (int e = 0; e < 8; e++) {
      int pk = g32 * 32 + ((e & 4) << 2) + g * 4 + (e & 3);
      tmp[e] = Vl[pk * 72 + db * 16 + li];
    }
    *(uint4*)(vfm + ((((size_t)bh * 32 + kt) * 8 + f) * 64 + l) * 8) = *(uint4*)tmp;
  }
}

// ---------------------------------------------------------------------------
// Flash attention (bf16 MFMA, fp32 online softmax).
// qkv[row][3072] bf16: q cols 0..1023, k 1024..2047 (h*64+d); V comes from vfm.
// Block: 4 waves x 16 q-rows = 64 q rows. KV tile = 64 keys.
// S^T = mfma(K_frag, Q_frag)  -> lane holds col q = lane&15, keys 4*(lane>>4)+r.
// Both K and V^T staged fragment-major via global_load_lds; all LDS reads are
// lane-linear uint4 (conflict-free). No ds_write anywhere.
// ---------------------------------------------------------------------------
__global__ __launch_bounds__(256) void attn_k(const u16* __restrict__ qkv,
                                              const u16* __restrict__ vfm,
                                              u16* __restrict__ ao) {
  __shared__ uint4 Ks[512];  // 8 frags x 64 x 16B (fragment-major K tile)
  __shared__ uint4 Vs[512];  // 8 frags x 64 x 16B (fragment-major V^T tile)
  const int t = threadIdx.x, lane = t & 63, wv = t >> 6;
  const int g = lane >> 4, li = lane & 15;
  const int bb = blockIdx.y >> 4, h = blockIdx.y & 15;
  const int q0 = blockIdx.x * 64 + wv * 16;

  const size_t qoff = (size_t)(bb * 2048 + q0 + li) * 3072 + h * 64 + g * 8;
  bf16x8 qf0 = __builtin_bit_cast(bf16x8, *(const uint4*)(qkv + qoff));
  bf16x8 qf1 = __builtin_bit_cast(bf16x8, *(const uint4*)(qkv + qoff + 32));

  // K staging sources (per-lane) for frags f0 = wv, f1 = wv + 4:
  // frag f: key_in_tile = (f>>1)*16 + li, d = (f&1)*32 + g*8
  const u16* kbase = qkv + (size_t)bb * 2048 * 3072 + 1024 + h * 64;
  const int f1 = wv + 4;
  const u16* ksrc0 = kbase + (size_t)(((wv >> 1) << 4) + li) * 3072 + ((wv & 1) << 5) + g * 8;
  const u16* ksrc1 = kbase + (size_t)(((f1 >> 1) << 4) + li) * 3072 + ((f1 & 1) << 5) + g * 8;
  // V^T staging sources: lane-linear in vfm
  const u16* vsrc0 = vfm + ((size_t)(bb * 16 + h) * 32) * 4096 + (wv * 64 + lane) * 8;
  const u16* vsrc1 = vsrc0 + 4 * 64 * 8;

  const f32x4 z4 = {0.f, 0.f, 0.f, 0.f};
  f32x4 Of[4];
#pragma unroll
  for (int db = 0; db < 4; db++) Of[db] = z4;
  float m_run = -INFINITY, l_run = 0.f;

  for (int tile = 0; tile < 32; tile++) {
    __syncthreads();  // previous tile's LDS reads done
    gload16(ksrc0 + (size_t)tile * 64 * 3072, (u16*)&Ks[wv * 64]);
    gload16(ksrc1 + (size_t)tile * 64 * 3072, (u16*)&Ks[(wv + 4) * 64]);
    gload16(vsrc0 + (size_t)tile * 4096, (u16*)&Vs[wv * 64]);
    gload16(vsrc1 + (size_t)tile * 4096, (u16*)&Vs[(wv + 4) * 64]);
    __syncthreads();  // vmcnt drained: tile ready

    // scores: S^T tiles (16 keys x 16 q), lane: q = li, keys = 4*g + r
    float sc[16];
    float mt = -INFINITY;
#pragma unroll
    for (int g32 = 0; g32 < 2; g32++) {
#pragma unroll
      for (int tt = 0; tt < 2; tt++) {
        int kb16 = g32 * 2 + tt;
        bf16x8 k0f = __builtin_bit_cast(bf16x8, Ks[(kb16 * 2 + 0) * 64 + lane]);
        bf16x8 k1f = __builtin_bit_cast(bf16x8, Ks[(kb16 * 2 + 1) * 64 + lane]);
        f32x4 st = z4;
        st = __builtin_amdgcn_mfma_f32_16x16x32_bf16(k0f, qf0, st, 0, 0, 0);
        st = __builtin_amdgcn_mfma_f32_16x16x32_bf16(k1f, qf1, st, 0, 0, 0);
#pragma unroll
        for (int r = 0; r < 4; r++) {
          float s = st[r] * 0.125f;
          sc[g32 * 8 + tt * 4 + r] = s;
          mt = fmaxf(mt, s);
        }
      }
    }
    mt = fmaxf(mt, __shfl_xor(mt, 16));
    mt = fmaxf(mt, __shfl_xor(mt, 32));
    float mn = fmaxf(m_run, mt);
    float aa = __expf(m_run - mn);
    float ps = 0.f;
#pragma unroll
    for (int i = 0; i < 16; i++) {
      float p = __expf(sc[i] - mn);
      sc[i] = p;
      ps += p;
    }
    ps += __shfl_xor(ps, 16);
    ps += __shfl_xor(ps, 32);
    l_run = l_run * aa + ps;
    m_run = mn;
    // rescale O: O rows are q = 4*g + r; a for that q held at lane (4*g+r)
    float a0 = __shfl(aa, g * 4 + 0);
    float a1 = __shfl(aa, g * 4 + 1);
    float a2 = __shfl(aa, g * 4 + 2);
    float a3 = __shfl(aa, g * 4 + 3);
#pragma unroll
    for (int db = 0; db < 4; db++) {
      Of[db][0] *= a0;
      Of[db][1] *= a1;
      Of[db][2] *= a2;
      Of[db][3] *= a3;
    }
    // PV: P(g32) is a K=32 A-frag (q rows = li, k = permuted keys)
#pragma unroll
    for (int g32 = 0; g32 < 2; g32++) {
      bf16x8 pf;
#pragma unroll
      for (int j = 0; j < 8; j++) pf[j] = (__bf16)sc[g32 * 8 + j];
#pragma unroll
      for (int db = 0; db < 4; db++) {
        bf16x8 vf = __builtin_bit_cast(bf16x8, Vs[(db * 2 + g32) * 64 + lane]);
        Of[db] = __builtin_amdgcn_mfma_f32_16x16x32_bf16(pf, vf, Of[db], 0, 0, 0);
      }
    }
  }

  float invl[4];
#pragma unroll
  for (int r = 0; r < 4; r++) invl[r] = 1.f / __shfl(l_run, g * 4 + r);
#pragma unroll
  for (int db = 0; db < 4; db++)
#pragma unroll
    for (int r = 0; r < 4; r++)
      ao[(size_t)(bb * 2048 + q0 + 4 * g + r) * 1024 + h * 64 + db * 16 + li] =
          f2bf(Of[db][r] * invl[r]);
}

// ---------------------------------------------------------------------------
// Launcher
// ---------------------------------------------------------------------------
extern "C" void kernel_launch(void* const* d_in, const int* in_sizes, int n_in,
                              void* d_out, int out_size, void* d_ws, size_t ws_size,
                              hipStream_t stream) {
  const float* x = (const float*)d_in[0];
  const float* ln1g = (const float*)d_in[1];
  const float* ln1b = (const float*)d_in[2];
  const float* wqkv = (const float*)d_in[3];
  const float* bqkv = (const float*)d_in[4];
  const float* wout = (const float*)d_in[5];
  const float* bout = (const float*)d_in[6];
  const float* ln2g = (const float*)d_in[7];
  const float* ln2b = (const float*)d_in[8];
  const float* wff1 = (const float*)d_in[9];
  const float* bff1 = (const float*)d_in[10];
  const float* wff2 = (const float*)d_in[11];
  const float* bff2 = (const float*)d_in[12];
  float* outF = (float*)d_out;
  char* ws = (char*)d_ws;

  u16* wqkvT = (u16*)(ws + 0);         // 3072x1024 bf16 : 6291456 B
  u16* woutT = (u16*)(ws + 6291456);   // 1024x1024 bf16 : 2097152 B
  u16* wff1T = (u16*)(ws + 8388608);   // 4096x1024 bf16 : 8388608 B
  u16* wff2T = (u16*)(ws + 16777216);  // 1024x4096 bf16 : 8388608 B
  u16* hbuf  = (u16*)(ws + 25165824);  // 8192x1024 bf16 : 16777216 B
  u16* vfm   = (u16*)(ws + 25165824);  // 16777216 B; overlays hbuf (dead qkv->ln2)
  u16* qkvb  = (u16*)(ws + 41943040);  // 8192x3072 bf16 : 50331648 B
  u16* attnb = (u16*)(ws + 92274688);  // 8192x1024 bf16 : 16777216 B
  u16* ffn1b = qkvb;                   // 8192x4096 bf16 overlays qkv+attn (dead by then)

  transpose_cvt<<<dim3(96, 32), 256, 0, stream>>>(wqkv, wqkvT, 1024, 3072);
  transpose_cvt<<<dim3(32, 32), 256, 0, stream>>>(wout, woutT, 1024, 1024);
  transpose_cvt<<<dim3(128, 32), 256, 0, stream>>>(wff1, wff1T, 1024, 4096);
  transpose_cvt<<<dim3(32, 128), 256, 0, stream>>>(wff2, wff2T, 4096, 1024);

  ln_k<<<8192, 256, 0, stream>>>(x, ln1g, ln1b, hbuf);
  gemm_bt<0><<<dim3(24, 64), 256, 0, stream>>>(hbuf, wqkvT, bqkv, nullptr, nullptr, qkvb,
                                               8192, 3072, 1024);
  v_tr<<<dim3(32, 64), 256, 0, stream>>>(qkvb, vfm);
  attn_k<<<dim3(32, 64), 256, 0, stream>>>(qkvb, vfm, attnb);
  gemm_bt<1><<<dim3(8, 64), 256, 0, stream>>>(attnb, woutT, bout, x, outF, nullptr,
                                              8192, 1024, 1024);
  ln_k<<<8192, 256, 0, stream>>>(outF, ln2g, ln2b, hbuf);
  gemm_bt<2><<<dim3(32, 64), 256, 0, stream>>>(hbuf, wff1T, bff1, nullptr, nullptr, ffn1b,
                                               8192, 4096, 1024);
  gemm_bt<1><<<dim3(8, 64), 256, 0, stream>>>(ffn1b, wff2T, bff2, outF, outF, nullptr,
                                              8192, 1024, 4096);

  (void)in_sizes;
  (void)n_in;
  (void)out_size;
  (void)ws_size;
}